// Round 1
// baseline (847.545 us; speedup 1.0000x reference)
//
#include <hip/hip_runtime.h>
#include <hip/hip_fp16.h>

#define NB 8
#define LL 2048
#define HH 1024

typedef unsigned short u16;
typedef __attribute__((ext_vector_type(8))) short short8;
typedef __attribute__((ext_vector_type(4))) float f32x4;

__device__ __forceinline__ u16 f2h(float f) {
  __half h = __float2half(f);
  return *reinterpret_cast<u16*>(&h);
}
__device__ __forceinline__ float h2f(u16 u) {
  __half h;
  *reinterpret_cast<u16*>(&h) = u;
  return __half2float(h);
}

__device__ __forceinline__ void gload16(const void* g, void* l) {
  __builtin_amdgcn_global_load_lds(
      (const __attribute__((address_space(1))) unsigned int*)g,
      (__attribute__((address_space(3))) unsigned int*)l, 16, 0, 0);
}

// C[M][N] = A[M][K] * Bop[N][K]^T  (both operands K-major fp16), fp32 accum.
// OUT_MODE: 0 = fp32 C, 1 = fp16 C. BIAS_MODE: 0 none, 1 per-col, 2 per-row.
// MASKED: write -inf where mask==0 (mask has same [row][col] geometry as C).
template<int OUT_MODE, int BIAS_MODE, bool MASKED>
__global__ __launch_bounds__(256)
void gemm128(const u16* __restrict__ A, const u16* __restrict__ Bm,
             float* __restrict__ Cf, u16* __restrict__ Ch,
             const float* __restrict__ bias, const int* __restrict__ mask,
             int M, int N, int K, int lda, int ldb, int ldc,
             long sA, long sB, long sC, long sMask, float scale)
{
  __shared__ u16 As[128 * 32];
  __shared__ u16 Bs[128 * 32];
  const int tid  = threadIdx.x;
  const int lane = tid & 63;
  const int wave = tid >> 6;
  const int wR = wave >> 1, wC = wave & 1;
  const int bx = blockIdx.x, by = blockIdx.y, bz = blockIdx.z;

  const u16* Ab = A  + (size_t)bz * sA;
  const u16* Bb = Bm + (size_t)bz * sB;

  // staging: thread t loads 16B; rows t>>2 (+64 for 2nd inst), col (t&3)*8
  const int srow = tid >> 2;
  const int scol = (tid & 3) << 3;
  const u16* gA = Ab + (size_t)(by * 128 + srow) * lda + scol;
  const u16* gB = Bb + (size_t)(bx * 128 + srow) * ldb + scol;
  u16* lA0 = &As[tid * 8];
  u16* lA1 = &As[2048 + tid * 8];
  u16* lB0 = &Bs[tid * 8];
  u16* lB1 = &Bs[2048 + tid * 8];
  const size_t a64 = (size_t)64 * lda, b64 = (size_t)64 * ldb;

  f32x4 acc[4][4];
#pragma unroll
  for (int m = 0; m < 4; ++m)
#pragma unroll
    for (int n = 0; n < 4; ++n) acc[m][n] = (f32x4)(0.f);

  const int fr = lane & 15;           // fragment row within 16
  const int kc = (lane >> 4) << 3;    // k-slice 0/8/16/24
  const u16* fA = &As[(wR * 64 + fr) * 32 + kc];
  const u16* fB = &Bs[(wC * 64 + fr) * 32 + kc];

  for (int k0 = 0; k0 < K; k0 += 32) {
    gload16(gA, lA0);
    gload16(gA + a64, lA1);
    gload16(gB, lB0);
    gload16(gB + b64, lB1);
    gA += 32; gB += 32;
    __syncthreads();   // drains vmcnt: staged tile visible
    short8 aF[4], bF[4];
#pragma unroll
    for (int m = 0; m < 4; ++m) aF[m] = *(const short8*)(fA + m * 512);
#pragma unroll
    for (int n = 0; n < 4; ++n) bF[n] = *(const short8*)(fB + n * 512);
#pragma unroll
    for (int m = 0; m < 4; ++m)
#pragma unroll
      for (int n = 0; n < 4; ++n)
        acc[m][n] = __builtin_amdgcn_mfma_f32_16x16x32_f16(aF[m], bF[n], acc[m][n], 0, 0, 0);
    __syncthreads();   // all reads done before next-iter staging
  }

  // C/D layout: col = lane&15, row = (lane>>4)*4 + r  [m89-verified]
  const int row0 = by * 128 + wR * 64 + ((lane >> 4) << 2);
  const int col0 = bx * 128 + wC * 64 + fr;
#pragma unroll
  for (int m = 0; m < 4; ++m) {
#pragma unroll
    for (int n = 0; n < 4; ++n) {
      const int col = col0 + n * 16;
      float bc = (BIAS_MODE == 1) ? bias[col] : 0.f;
#pragma unroll
      for (int r = 0; r < 4; ++r) {
        const int row = row0 + m * 16 + r;
        float v = acc[m][n][r] * scale;
        if (BIAS_MODE == 1) v += bc;
        else if (BIAS_MODE == 2) v += bias[row];
        if (MASKED) {
          int mk = mask[(size_t)bz * sMask + (size_t)row * ldc + col];
          if (mk == 0) v = -INFINITY;
        }
        size_t idx = (size_t)bz * sC + (size_t)row * ldc + col;
        if (OUT_MODE == 0) Cf[idx] = v;
        else               Ch[idx] = f2h(v);
      }
    }
  }
}

__global__ __launch_bounds__(256)
void cvt_f32_f16(const float* __restrict__ x, u16* __restrict__ y, int n4) {
  int i = blockIdx.x * 256 + threadIdx.x;
  if (i >= n4) return;
  float4 v = ((const float4*)x)[i];
  ushort4 o;
  o.x = f2h(v.x); o.y = f2h(v.y); o.z = f2h(v.z); o.w = f2h(v.w);
  ((ushort4*)y)[i] = o;
}

// WT[n][k] = (fp16) W[k][n], W is HH x HH fp32
__global__ __launch_bounds__(256)
void wtrans(const float* __restrict__ W, u16* __restrict__ WT) {
  __shared__ float t[32][33];
  const int tx = threadIdx.x & 31, ty = threadIdx.x >> 5;
  const int bx = blockIdx.x, by = blockIdx.y;
#pragma unroll
  for (int i = 0; i < 4; ++i)
    t[ty + i * 8][tx] = W[(size_t)(by * 32 + ty + i * 8) * HH + bx * 32 + tx];
  __syncthreads();
#pragma unroll
  for (int i = 0; i < 4; ++i)
    WT[(size_t)(bx * 32 + ty + i * 8) * HH + by * 32 + tx] = f2h(t[tx][ty + i * 8]);
}

// in-place row softmax over fp16 scores (masked entries already -inf); row len LL
__global__ __launch_bounds__(256)
void softmax_rows(u16* __restrict__ S) {
  const int tid = threadIdx.x, lane = tid & 63, wv = tid >> 6;
  u16* p = S + (size_t)blockIdx.x * LL + tid * 8;
  short8 raw = *(const short8*)p;
  float v[8];
#pragma unroll
  for (int j = 0; j < 8; ++j) v[j] = h2f((u16)raw[j]);
  float m = v[0];
#pragma unroll
  for (int j = 1; j < 8; ++j) m = fmaxf(m, v[j]);
  for (int off = 32; off; off >>= 1) m = fmaxf(m, __shfl_xor(m, off));
  __shared__ float rM[4], rS[4];
  if (lane == 0) rM[wv] = m;
  __syncthreads();
  m = fmaxf(fmaxf(rM[0], rM[1]), fmaxf(rM[2], rM[3]));
  float e[8], s = 0.f;
#pragma unroll
  for (int j = 0; j < 8; ++j) { e[j] = __expf(v[j] - m); s += e[j]; }
  for (int off = 32; off; off >>= 1) s += __shfl_xor(s, off);
  if (lane == 0) rS[wv] = s;
  __syncthreads();
  s = rS[0] + rS[1] + rS[2] + rS[3];
  float inv = 1.f / s;
  short8 o;
#pragma unroll
  for (int j = 0; j < 8; ++j) o[j] = (short)f2h(e[j] * inv);
  *(short8*)p = o;
}

// in-place LayerNorm over last dim (HH) of fp32 X
__global__ __launch_bounds__(256)
void layernorm_rows(float* __restrict__ X, const float* __restrict__ g,
                    const float* __restrict__ be) {
  const int tid = threadIdx.x, lane = tid & 63, wv = tid >> 6;
  float* p = X + (size_t)blockIdx.x * HH + tid * 4;
  float4 v = *(const float4*)p;
  float s = v.x + v.y + v.z + v.w;
  float q = v.x * v.x + v.y * v.y + v.z * v.z + v.w * v.w;
  for (int off = 32; off; off >>= 1) { s += __shfl_xor(s, off); q += __shfl_xor(q, off); }
  __shared__ float rA[4], rB[4];
  if (lane == 0) { rA[wv] = s; rB[wv] = q; }
  __syncthreads();
  s = rA[0] + rA[1] + rA[2] + rA[3];
  q = rB[0] + rB[1] + rB[2] + rB[3];
  const float mu = s * (1.f / HH);
  const float var = q * (1.f / HH) - mu * mu;
  const float rs = rsqrtf(var + 1e-5f);
  const int c = tid * 4;
  float4 o;
  o.x = (v.x - mu) * rs * g[c + 0] + be[c + 0];
  o.y = (v.y - mu) * rs * g[c + 1] + be[c + 1];
  o.z = (v.z - mu) * rs * g[c + 2] + be[c + 2];
  o.w = (v.w - mu) * rs * g[c + 3] + be[c + 3];
  *(float4*)p = o;
}

extern "C" void kernel_launch(void* const* d_in, const int* in_sizes, int n_in,
                              void* d_out, int out_size, void* d_ws, size_t ws_size,
                              hipStream_t stream)
{
  const float* queries = (const float*)d_in[0];
  const float* keys    = (const float*)d_in[1];
  const float* values  = (const float*)d_in[2];
  const int*   mask    = (const int*)d_in[3];
  const float* Wq = (const float*)d_in[4];
  const float* bq = (const float*)d_in[5];
  const float* Wk = (const float*)d_in[6];
  const float* bk = (const float*)d_in[7];
  const float* Wv = (const float*)d_in[8];
  const float* bv = (const float*)d_in[9];
  const float* g  = (const float*)d_in[10];
  const float* be = (const float*)d_in[11];
  float* out = (float*)d_out;

  char* ws = (char*)d_ws;
  const size_t MB = (size_t)1 << 20;
  u16* WqT = (u16*)(ws + 0 * MB);     // 2 MB  [HH][HH] fp16, Wq^T
  u16* WkT = (u16*)(ws + 2 * MB);     // 2 MB
  u16* WvT = (u16*)(ws + 4 * MB);     // 2 MB
  u16* Xh  = (u16*)(ws + 6 * MB);     // 32 MB [B*L][HH] fp16 (reused input buf)
  u16* Qp  = (u16*)(ws + 38 * MB);    // 32 MB [B*L][HH] fp16
  u16* Kp  = (u16*)(ws + 70 * MB);    // 32 MB [B*L][HH] fp16
  u16* VT  = (u16*)(ws + 102 * MB);   // 32 MB [HH][B*L] fp16 (V transposed)
  u16* S   = (u16*)(ws + 134 * MB);   // 64 MB [B][L][L] fp16 scores -> probs

  const int BL = NB * LL;             // 16384
  const int n4 = BL * HH / 4;         // fp32->fp16 convert chunks

  wtrans<<<dim3(32, 32), 256, 0, stream>>>(Wq, WqT);
  wtrans<<<dim3(32, 32), 256, 0, stream>>>(Wk, WkT);
  wtrans<<<dim3(32, 32), 256, 0, stream>>>(Wv, WvT);

  // Q = queries @ Wq + bq   -> Qp fp16 [BL][HH]
  cvt_f32_f16<<<n4 / 256, 256, 0, stream>>>(queries, Xh, n4);
  gemm128<1, 1, false><<<dim3(HH / 128, BL / 128, 1), 256, 0, stream>>>(
      Xh, WqT, nullptr, Qp, bq, nullptr,
      BL, HH, HH, HH, HH, HH, 0, 0, 0, 0, 1.f);

  // K = keys @ Wk + bk      -> Kp fp16 [BL][HH]
  cvt_f32_f16<<<n4 / 256, 256, 0, stream>>>(keys, Xh, n4);
  gemm128<1, 1, false><<<dim3(HH / 128, BL / 128, 1), 256, 0, stream>>>(
      Xh, WkT, nullptr, Kp, bk, nullptr,
      BL, HH, HH, HH, HH, HH, 0, 0, 0, 0, 1.f);

  // V^T = Wv^T @ X^T + bv   -> VT fp16 [HH][BL]  (V[j][n] at VT[n][j])
  cvt_f32_f16<<<n4 / 256, 256, 0, stream>>>(values, Xh, n4);
  gemm128<1, 2, false><<<dim3(BL / 128, HH / 128, 1), 256, 0, stream>>>(
      WvT, Xh, nullptr, VT, bv, nullptr,
      HH, BL, HH, HH, HH, BL, 0, 0, 0, 0, 1.f);

  // scores = (Qp Kp^T)/32, mask==0 -> -inf, fp16 [B][L][L]
  gemm128<1, 0, true><<<dim3(LL / 128, LL / 128, NB), 256, 0, stream>>>(
      Qp, Kp, nullptr, S, nullptr, mask,
      LL, LL, HH, HH, HH, LL,
      (long)LL * HH, (long)LL * HH, (long)LL * LL, (long)LL * LL, 1.f / 32.f);

  // softmax rows in place
  softmax_rows<<<NB * LL, 256, 0, stream>>>(S);

  // context = P @ V -> fp32 d_out [B][L][HH]   (B-operand = VT, per-batch col offset)
  gemm128<0, 0, false><<<dim3(HH / 128, LL / 128, NB), 256, 0, stream>>>(
      S, VT, out, nullptr, nullptr, nullptr,
      LL, HH, LL, LL, BL, HH,
      (long)LL * LL, (long)LL, (long)LL * HH, 0, 1.f);

  // LayerNorm in place on d_out
  layernorm_rows<<<NB * LL, 256, 0, stream>>>(out, g, be);
}

// Round 2
// 643.282 us; speedup vs baseline: 1.3175x; 1.3175x over previous
//
#include <hip/hip_runtime.h>
#include <hip/hip_fp16.h>

#define NB 8
#define LL 2048
#define HH 1024

typedef unsigned short u16;
typedef __attribute__((ext_vector_type(8))) short short8;
typedef __attribute__((ext_vector_type(4))) float f32x4;

__device__ __forceinline__ u16 f2h(float f) { __half h = __float2half(f); return *reinterpret_cast<u16*>(&h); }
__device__ __forceinline__ float h2f(u16 u) { __half h; *reinterpret_cast<u16*>(&h) = u; return __half2float(h); }

__device__ __forceinline__ void gload16(const void* g, void* l) {
  __builtin_amdgcn_global_load_lds(
      (const __attribute__((address_space(1))) unsigned int*)g,
      (__attribute__((address_space(3))) unsigned int*)l, 16, 0, 0);
}

// Stage one half-tile (128 rows x 64 cols fp16 = 16KB) of a K-major operand.
// LDS layout: [256 rows][8 chunks of 16B], swizzled: chunk' = chunk ^ (row&7).
// gload_lds dest is linear (base + tid*16); the swizzle is applied by permuting
// the GLOBAL source chunk (both-sides rule): slot s=j*512+tid -> row=s>>3,
// chunk'=s&7, global chunk = chunk' ^ (row&7).
__device__ __forceinline__ void stage_half(const u16* __restrict__ gsrc, int ld,
                                           char* smem, int bufbase, int h, int tt,
                                           int tid, int row0s, int row1s, int gch0, int gch1) {
  const u16* p0 = gsrc + (size_t)(h * 128 + row0s) * ld + tt * 64 + gch0 * 8;
  const u16* p1 = gsrc + (size_t)(h * 128 + row1s) * ld + tt * 64 + gch1 * 8;
  gload16(p0, smem + bufbase + h * 16384 + tid * 16);
  gload16(p1, smem + bufbase + h * 16384 + 8192 + tid * 16);
}

// Swizzled fragment read: 16B of row `row` (within 256-row buf), k-slice kk, lane (fr,g)
__device__ __forceinline__ short8 fragld(const char* smem, int bufbase, int row, int kk, int fr, int g) {
  const int byte = bufbase + row * 128 + (((kk * 4 + g) ^ (fr & 7)) << 4);
  return *reinterpret_cast<const short8*>(smem + byte);
}

// 256x256, BK=64, 8-wave (2x4), 4 quadrant-phases/K-tile, counted vmcnt(4).
// C[M][N] = A[M][K] * B[N][K]^T, fp16 operands (K-major), fp32 accum.
// OUT_MODE: 0 fp32, 1 fp16. BIAS_MODE: 0 none, 1 per-col, 2 per-row.
template<int OUT_MODE, int BIAS_MODE, bool MASKED>
__global__ __launch_bounds__(512, 2)
void gemm256(const u16* __restrict__ A, const u16* __restrict__ Bm,
             float* __restrict__ Cf, u16* __restrict__ Ch,
             const float* __restrict__ bias, const int* __restrict__ mask,
             int gx, int gxy, int K, int lda, int ldb, int ldc,
             long sA, long sB, long sC, long sMask, float scale)
{
  extern __shared__ char smem[];
  // A bufs at 0 / 32768 ; B bufs at 65536 / 98304  (128 KB total)
  const int tid = threadIdx.x;
  const int lane = tid & 63;
  const int wid = tid >> 6;
  const int wr = wid >> 2, wc = wid & 3;
  const int fr = lane & 15, g = lane >> 4;

  // XCD-aware bijective swizzle (all launches have gridDim.x % 8 == 0)
  const int nwg = gridDim.x;
  const int q8 = nwg >> 3;
  const int swz = (blockIdx.x & 7) * q8 + (blockIdx.x >> 3);
  const int bz = swz / gxy;
  const int rrm = swz - bz * gxy;
  const int by = rrm / gx;
  const int bx = rrm - by * gx;

  const u16* gA = A + (size_t)bz * sA + (size_t)(by * 256) * lda;
  const u16* gB = Bm + (size_t)bz * sB + (size_t)(bx * 256) * ldb;

  const int s1 = 512 + tid;
  const int row0s = tid >> 3, row1s = s1 >> 3;
  const int gch0 = (tid & 7) ^ (row0s & 7);
  const int gch1 = (s1 & 7) ^ (row1s & 7);

  f32x4 acc[8][4];
#pragma unroll
  for (int m = 0; m < 8; ++m)
#pragma unroll
    for (int n = 0; n < 4; ++n) acc[m][n] = (f32x4)(0.f);

  const int arow = wr * 128 + fr;  // + m*16 (mLow), +64+m*16 (mHigh)
  const int brow = wc * 64 + fr;   // + n*16
  const int nt = K >> 6;

  // ---- prologue: tile0.B, tile0.A -> buf0 ; tile1.B -> buf1 (12 insts/wave? 4/wave each) ----
  stage_half(gB, ldb, smem, 65536, 0, 0, tid, row0s, row1s, gch0, gch1);
  stage_half(gB, ldb, smem, 65536, 1, 0, tid, row0s, row1s, gch0, gch1);
  stage_half(gA, lda, smem, 0,     0, 0, tid, row0s, row1s, gch0, gch1);
  stage_half(gA, lda, smem, 0,     1, 0, tid, row0s, row1s, gch0, gch1);
  stage_half(gB, ldb, smem, 98304, 0, 1, tid, row0s, row1s, gch0, gch1);
  stage_half(gB, ldb, smem, 98304, 1, 1, tid, row0s, row1s, gch0, gch1);
  asm volatile("s_waitcnt vmcnt(4)" ::: "memory");  // tile0 landed; tile1.B (4 insts) in flight
  __builtin_amdgcn_s_barrier();

  for (int t = 0; t < nt; ++t) {
    const int ca = (t & 1) ? 32768 : 0;
    const int cb = 65536 + ((t & 1) ? 32768 : 0);
    const int na = ca ^ 32768;
    short8 aL[4], aH[4], b0[4], b1[4];

    // ---- P1: mLow x kk0 ---- (stage next-tile A half0 -> other buf: always safe)
#pragma unroll
    for (int m = 0; m < 4; ++m) aL[m] = fragld(smem, ca, arow + m * 16, 0, fr, g);
#pragma unroll
    for (int n = 0; n < 4; ++n) b0[n] = fragld(smem, cb, brow + n * 16, 0, fr, g);
    if (t + 1 < nt) stage_half(gA, lda, smem, na, 0, t + 1, tid, row0s, row1s, gch0, gch1);
    __builtin_amdgcn_s_barrier();
    asm volatile("s_waitcnt lgkmcnt(0)" ::: "memory");
    __builtin_amdgcn_s_setprio(1);
#pragma unroll
    for (int m = 0; m < 4; ++m)
#pragma unroll
      for (int n = 0; n < 4; ++n)
        acc[m][n] = __builtin_amdgcn_mfma_f32_16x16x32_f16(aL[m], b0[n], acc[m][n], 0, 0, 0);
    __builtin_amdgcn_s_setprio(0);
    __builtin_amdgcn_s_barrier();

    // ---- P2: mLow x kk1 ----
#pragma unroll
    for (int m = 0; m < 4; ++m) aH[m] = fragld(smem, ca, arow + m * 16, 1, fr, g);
#pragma unroll
    for (int n = 0; n < 4; ++n) b1[n] = fragld(smem, cb, brow + n * 16, 1, fr, g);
    if (t + 1 < nt) stage_half(gA, lda, smem, na, 1, t + 1, tid, row0s, row1s, gch0, gch1);
    __builtin_amdgcn_s_barrier();
    asm volatile("s_waitcnt lgkmcnt(0)" ::: "memory");
    __builtin_amdgcn_s_setprio(1);
#pragma unroll
    for (int m = 0; m < 4; ++m)
#pragma unroll
      for (int n = 0; n < 4; ++n)
        acc[m][n] = __builtin_amdgcn_mfma_f32_16x16x32_f16(aH[m], b1[n], acc[m][n], 0, 0, 0);
    __builtin_amdgcn_s_setprio(0);
    __builtin_amdgcn_s_barrier();

    // ---- P3: mHigh x kk0 ---- (stage tile t+2 B half0 into CURRENT B buf:
    // safe — all waves' B reads of this buf completed before P2's trailing barrier)
#pragma unroll
    for (int m = 0; m < 4; ++m) aL[m] = fragld(smem, ca, arow + 64 + m * 16, 0, fr, g);
    if (t + 2 < nt) stage_half(gB, ldb, smem, cb, 0, t + 2, tid, row0s, row1s, gch0, gch1);
    __builtin_amdgcn_s_barrier();
    asm volatile("s_waitcnt lgkmcnt(0)" ::: "memory");
    __builtin_amdgcn_s_setprio(1);
#pragma unroll
    for (int m = 0; m < 4; ++m)
#pragma unroll
      for (int n = 0; n < 4; ++n)
        acc[4 + m][n] = __builtin_amdgcn_mfma_f32_16x16x32_f16(aL[m], b0[n], acc[4 + m][n], 0, 0, 0);
    __builtin_amdgcn_s_setprio(0);
    __builtin_amdgcn_s_barrier();

    // ---- P4: mHigh x kk1 ----
#pragma unroll
    for (int m = 0; m < 4; ++m) aH[m] = fragld(smem, ca, arow + 64 + m * 16, 1, fr, g);
    if (t + 2 < nt) stage_half(gB, ldb, smem, cb, 1, t + 2, tid, row0s, row1s, gch0, gch1);
    __builtin_amdgcn_s_barrier();
    asm volatile("s_waitcnt lgkmcnt(0)" ::: "memory");
    __builtin_amdgcn_s_setprio(1);
#pragma unroll
    for (int m = 0; m < 4; ++m)
#pragma unroll
      for (int n = 0; n < 4; ++n)
        acc[4 + m][n] = __builtin_amdgcn_mfma_f32_16x16x32_f16(aH[m], b1[n], acc[4 + m][n], 0, 0, 0);
    __builtin_amdgcn_s_setprio(0);
    // tile-end counted wait: newest 4 insts = t+2.B (still in flight); t+1.A + older landed
    if (t + 2 < nt)      { asm volatile("s_waitcnt vmcnt(4)" ::: "memory"); }
    else if (t + 1 < nt) { asm volatile("s_waitcnt vmcnt(0)" ::: "memory"); }
    __builtin_amdgcn_s_barrier();
  }

  // ---- epilogue: C/D layout col=lane&15, row=(lane>>4)*4+r ----
  const int row0 = by * 256 + wr * 128 + (g << 2);
  const int col0 = bx * 256 + wc * 64 + fr;
#pragma unroll
  for (int m = 0; m < 8; ++m) {
#pragma unroll
    for (int n = 0; n < 4; ++n) {
      const int col = col0 + n * 16;
      float bc = (BIAS_MODE == 1) ? bias[col] : 0.f;
#pragma unroll
      for (int r = 0; r < 4; ++r) {
        const int row = row0 + m * 16 + r;
        float v = acc[m][n][r] * scale;
        if (BIAS_MODE == 1) v += bc;
        else if (BIAS_MODE == 2) v += bias[row];
        if (MASKED) {
          int mk = mask[(size_t)bz * sMask + (size_t)row * ldc + col];
          if (mk == 0) v = -INFINITY;
        }
        size_t idx = (size_t)bz * sC + (size_t)row * ldc + col;
        if (OUT_MODE == 0) Cf[idx] = v;
        else               Ch[idx] = f2h(v);
      }
    }
  }
}

__global__ __launch_bounds__(256)
void cvt_f32_f16(const float* __restrict__ x, u16* __restrict__ y, int n4) {
  int i = blockIdx.x * 256 + threadIdx.x;
  if (i >= n4) return;
  float4 v = ((const float4*)x)[i];
  ushort4 o;
  o.x = f2h(v.x); o.y = f2h(v.y); o.z = f2h(v.z); o.w = f2h(v.w);
  ((ushort4*)y)[i] = o;
}

__global__ __launch_bounds__(256)
void wtrans(const float* __restrict__ W, u16* __restrict__ WT) {
  __shared__ float t[32][33];
  const int tx = threadIdx.x & 31, ty = threadIdx.x >> 5;
  const int bx = blockIdx.x, by = blockIdx.y;
#pragma unroll
  for (int i = 0; i < 4; ++i)
    t[ty + i * 8][tx] = W[(size_t)(by * 32 + ty + i * 8) * HH + bx * 32 + tx];
  __syncthreads();
#pragma unroll
  for (int i = 0; i < 4; ++i)
    WT[(size_t)(bx * 32 + ty + i * 8) * HH + by * 32 + tx] = f2h(t[tx][ty + i * 8]);
}

__global__ __launch_bounds__(256)
void softmax_rows(u16* __restrict__ S) {
  const int tid = threadIdx.x, lane = tid & 63, wv = tid >> 6;
  u16* p = S + (size_t)blockIdx.x * LL + tid * 8;
  short8 raw = *(const short8*)p;
  float v[8];
#pragma unroll
  for (int j = 0; j < 8; ++j) v[j] = h2f((u16)raw[j]);
  float m = v[0];
#pragma unroll
  for (int j = 1; j < 8; ++j) m = fmaxf(m, v[j]);
  for (int off = 32; off; off >>= 1) m = fmaxf(m, __shfl_xor(m, off));
  __shared__ float rM[4], rS[4];
  if (lane == 0) rM[wv] = m;
  __syncthreads();
  m = fmaxf(fmaxf(rM[0], rM[1]), fmaxf(rM[2], rM[3]));
  float e[8], s = 0.f;
#pragma unroll
  for (int j = 0; j < 8; ++j) { e[j] = __expf(v[j] - m); s += e[j]; }
  for (int off = 32; off; off >>= 1) s += __shfl_xor(s, off);
  if (lane == 0) rS[wv] = s;
  __syncthreads();
  s = rS[0] + rS[1] + rS[2] + rS[3];
  float inv = 1.f / s;
  short8 o;
#pragma unroll
  for (int j = 0; j < 8; ++j) o[j] = (short)f2h(e[j] * inv);
  *(short8*)p = o;
}

__global__ __launch_bounds__(256)
void layernorm_rows(float* __restrict__ X, const float* __restrict__ g,
                    const float* __restrict__ be) {
  const int tid = threadIdx.x, lane = tid & 63, wv = tid >> 6;
  float* p = X + (size_t)blockIdx.x * HH + tid * 4;
  float4 v = *(const float4*)p;
  float s = v.x + v.y + v.z + v.w;
  float q = v.x * v.x + v.y * v.y + v.z * v.z + v.w * v.w;
  for (int off = 32; off; off >>= 1) { s += __shfl_xor(s, off); q += __shfl_xor(q, off); }
  __shared__ float rA[4], rB[4];
  if (lane == 0) { rA[wv] = s; rB[wv] = q; }
  __syncthreads();
  s = rA[0] + rA[1] + rA[2] + rA[3];
  q = rB[0] + rB[1] + rB[2] + rB[3];
  const float mu = s * (1.f / HH);
  const float var = q * (1.f / HH) - mu * mu;
  const float rs = rsqrtf(var + 1e-5f);
  const int c = tid * 4;
  float4 o;
  o.x = (v.x - mu) * rs * g[c + 0] + be[c + 0];
  o.y = (v.y - mu) * rs * g[c + 1] + be[c + 1];
  o.z = (v.z - mu) * rs * g[c + 2] + be[c + 2];
  o.w = (v.w - mu) * rs * g[c + 3] + be[c + 3];
  *(float4*)p = o;
}

extern "C" void kernel_launch(void* const* d_in, const int* in_sizes, int n_in,
                              void* d_out, int out_size, void* d_ws, size_t ws_size,
                              hipStream_t stream)
{
  const float* queries = (const float*)d_in[0];
  const float* keys    = (const float*)d_in[1];
  const float* values  = (const float*)d_in[2];
  const int*   mask    = (const int*)d_in[3];
  const float* Wq = (const float*)d_in[4];
  const float* bq = (const float*)d_in[5];
  const float* Wk = (const float*)d_in[6];
  const float* bk = (const float*)d_in[7];
  const float* Wv = (const float*)d_in[8];
  const float* bv = (const float*)d_in[9];
  const float* g  = (const float*)d_in[10];
  const float* be = (const float*)d_in[11];
  float* out = (float*)d_out;

  char* ws = (char*)d_ws;
  const size_t MB = (size_t)1 << 20;
  u16* WqT = (u16*)(ws + 0 * MB);
  u16* WkT = (u16*)(ws + 2 * MB);
  u16* WvT = (u16*)(ws + 4 * MB);
  u16* Xh  = (u16*)(ws + 6 * MB);
  u16* Qp  = (u16*)(ws + 38 * MB);
  u16* Kp  = (u16*)(ws + 70 * MB);
  u16* VT  = (u16*)(ws + 102 * MB);   // [HH][B*L] fp16
  u16* S   = (u16*)(ws + 134 * MB);   // [B][L][L] fp16

  const int BL = NB * LL;
  const int n4 = BL * HH / 4;
  const size_t SH = 131072;

  wtrans<<<dim3(32, 32), 256, 0, stream>>>(Wq, WqT);
  wtrans<<<dim3(32, 32), 256, 0, stream>>>(Wk, WkT);
  wtrans<<<dim3(32, 32), 256, 0, stream>>>(Wv, WvT);

  // Q = queries @ Wq + bq
  cvt_f32_f16<<<n4 / 256, 256, 0, stream>>>(queries, Xh, n4);
  gemm256<1, 1, false><<<(BL / 256) * (HH / 256), 512, SH, stream>>>(
      Xh, WqT, nullptr, Qp, bq, nullptr,
      HH / 256, (HH / 256) * (BL / 256), HH, HH, HH, HH, 0, 0, 0, 0, 1.f);

  // K = keys @ Wk + bk
  cvt_f32_f16<<<n4 / 256, 256, 0, stream>>>(keys, Xh, n4);
  gemm256<1, 1, false><<<(BL / 256) * (HH / 256), 512, SH, stream>>>(
      Xh, WkT, nullptr, Kp, bk, nullptr,
      HH / 256, (HH / 256) * (BL / 256), HH, HH, HH, HH, 0, 0, 0, 0, 1.f);

  // V^T = Wv^T @ X^T + bv (per-row bias) -> VT [HH][BL]
  cvt_f32_f16<<<n4 / 256, 256, 0, stream>>>(values, Xh, n4);
  gemm256<1, 2, false><<<(HH / 256) * (BL / 256), 512, SH, stream>>>(
      WvT, Xh, nullptr, VT, bv, nullptr,
      BL / 256, (BL / 256) * (HH / 256), HH, HH, HH, BL, 0, 0, 0, 0, 1.f);

  // scores = (Qp Kp^T)/32 with mask -> S fp16
  gemm256<1, 0, true><<<(LL / 256) * (LL / 256) * NB, 512, SH, stream>>>(
      Qp, Kp, nullptr, S, nullptr, mask,
      LL / 256, (LL / 256) * (LL / 256), HH, HH, HH, LL,
      (long)LL * HH, (long)LL * HH, (long)LL * LL, (long)LL * LL, 1.f / 32.f);

  softmax_rows<<<NB * LL, 256, 0, stream>>>(S);

  // context = P @ V -> fp32 d_out
  gemm256<0, 0, false><<<(LL / 256) * (HH / 256) * NB, 512, SH, stream>>>(
      S, VT, out, nullptr, nullptr, nullptr,
      HH / 256, (HH / 256) * (LL / 256), LL, LL, BL, HH,
      (long)LL * LL, (long)LL, (long)LL * HH, 0, 1.f);

  layernorm_rows<<<NB * LL, 256, 0, stream>>>(out, g, be);
}